// Round 2
// baseline (688.180 us; speedup 1.0000x reference)
//
#include <hip/hip_runtime.h>
#include <math.h>

typedef __bf16 bf16;
typedef bf16 bf16x4 __attribute__((ext_vector_type(4)));
typedef bf16 bf16x8 __attribute__((ext_vector_type(8)));
typedef float f32x4 __attribute__((ext_vector_type(4)));

#define T_TOK   1024
#define H_DIM   2048
#define I_DIM   1024
#define NPAIR_R 4096
#define NPAIR   5120
#define BK      32
#define LDSS    40            // 80B row stride: 16B-aligned, b128 reads 2-way (free)
#define ABUF    10240         // 128*40*2 bytes per matrix per buffer
#define BUFSZ   20480         // As+Bs for one stage buffer
#define SMEM_SZ 40960         // 2 stage buffers; epilogue u_lds (33280B) fits

__device__ inline bf16x8 cvt8(const float4 a, const float4 b) {
  bf16x8 r;
  r[0] = (bf16)a.x; r[1] = (bf16)a.y; r[2] = (bf16)a.z; r[3] = (bf16)a.w;
  r[4] = (bf16)b.x; r[5] = (bf16)b.y; r[6] = (bf16)b.z; r[7] = (bf16)b.w;
  return r;
}

// ---------------- router ----------------
__global__ __launch_bounds__(256) void router_kernel(
    const float* __restrict__ x, const float* __restrict__ gate_w,
    const float* __restrict__ e_bias,
    int* __restrict__ topk_ids, float* __restrict__ topk_w,
    int* __restrict__ counts)
{
  int t = blockIdx.x;
  int tid = threadIdx.x;
  float acc[16];
#pragma unroll
  for (int e = 0; e < 16; ++e) acc[e] = 0.f;
  const float* xr = x + (size_t)t * H_DIM;
  for (int h = tid; h < H_DIM; h += 256) {
    float xv = xr[h];
#pragma unroll
    for (int e = 0; e < 16; ++e) acc[e] += xv * gate_w[e * H_DIM + h];
  }
#pragma unroll
  for (int e = 0; e < 16; ++e) {
#pragma unroll
    for (int off = 32; off >= 1; off >>= 1)
      acc[e] += __shfl_down(acc[e], off, 64);
  }
  __shared__ float red[4][16];
  int lane = tid & 63, wave = tid >> 6;
  if (lane == 0) {
#pragma unroll
    for (int e = 0; e < 16; ++e) red[wave][e] = acc[e];
  }
  __syncthreads();
  if (tid == 0) {
    float scores[16], sb[16];
    for (int e = 0; e < 16; ++e) {
      float l = red[0][e] + red[1][e] + red[2][e] + red[3][e];
      float s = 1.f / (1.f + expf(-l));
      scores[e] = s;
      sb[e] = s + e_bias[e];
    }
    float gs[4];
    for (int g = 0; g < 4; ++g) {
      float b1 = -1e30f, b2 = -1e30f;
      for (int j = 0; j < 4; ++j) {
        float v = sb[g * 4 + j];
        if (v > b1) { b2 = b1; b1 = v; }
        else if (v > b2) b2 = v;
      }
      gs[g] = b1 + b2;
    }
    int g1 = 0; float bv = gs[0];
    for (int g = 1; g < 4; ++g) if (gs[g] > bv) { bv = gs[g]; g1 = g; }
    int g2 = -1; float bv2 = -1e30f;
    for (int g = 0; g < 4; ++g) if (g != g1 && gs[g] > bv2) { bv2 = gs[g]; g2 = g; }
    float tmp[16];
    for (int e = 0; e < 16; ++e) {
      int grp = e >> 2;
      tmp[e] = (grp == g1 || grp == g2) ? sb[e] : 0.0f;
    }
    bool used[16] = {false};
    int ids[4]; float wv[4]; float wsum = 0.f;
    for (int k = 0; k < 4; ++k) {
      int bi = 0; float bvv = -1e30f;
      for (int i = 0; i < 16; ++i)
        if (!used[i] && tmp[i] > bvv) { bvv = tmp[i]; bi = i; }
      used[bi] = true;
      ids[k] = bi; wv[k] = scores[bi]; wsum += scores[bi];
    }
    float inv = 1.f / wsum;
    for (int k = 0; k < 4; ++k) {
      topk_ids[t * 4 + k] = ids[k];
      topk_w[t * 4 + k] = wv[k] * inv;
      atomicAdd(&counts[ids[k]], 1);
    }
  }
}

// ---------------- offsets ----------------
__global__ void offsets_kernel(const int* __restrict__ counts, int* __restrict__ off)
{
  if (threadIdx.x == 0 && blockIdx.x == 0) {
    int s = 0;
    for (int e = 0; e < 16; ++e) { off[e] = s; s += counts[e]; }
    off[16] = s;
  }
}

// ---------------- scatter + inverse map ----------------
__global__ __launch_bounds__(256) void scatter_kernel(
    const int* __restrict__ topk_ids, const float* __restrict__ topk_w,
    const int* __restrict__ off, int* __restrict__ cursor,
    int* __restrict__ pair_token, float* __restrict__ pair_scale,
    int* __restrict__ inv_pair)
{
  int i = blockIdx.x * 256 + threadIdx.x;
  if (i < NPAIR_R) {
    int e = topk_ids[i];
    float w = topk_w[i];
    int pos = atomicAdd(&cursor[e], 1);
    int idx = off[e] + pos;
    int t = i >> 2;
    pair_token[idx] = t;
    pair_scale[idx] = 2.5f * w;
    inv_pair[t * 5 + (i & 3)] = idx;
  } else if (i < NPAIR) {
    int t = i - NPAIR_R;
    pair_token[i] = t;           // shared expert: identity token list
    pair_scale[i] = 1.0f;
    inv_pair[t * 5 + 4] = i;
  }
}

// ---------------- fused gate_up GEMM + SiLU*mul ----------------
// Block computes a_buf[pair rows mt*128.., cols nt*64 .. nt*64+64)
// B-tile rows: [nt*64, nt*64+64) = gate rows, [1024+nt*64, ..+64) = up rows.
__global__ __launch_bounds__(256) void gateup_silu_kernel(
    const float* __restrict__ x, const float* __restrict__ w_gu,
    const float* __restrict__ s_wgu,
    const int* __restrict__ off, const int* __restrict__ pair_token,
    bf16* __restrict__ a_buf)
{
  const int nt = blockIdx.x;   // 0..15 over I (64 a-cols each)
  const int mt = blockIdx.y;   // 0..7
  const int e  = blockIdx.z;   // 0..16 (16 = shared)
  const int poff = (e < 16) ? off[e]     : NPAIR_R;
  const int pend = (e < 16) ? off[e + 1] : NPAIR;
  const int cnt  = pend - poff;
  if (mt * 128 >= cnt) return;
  const float* __restrict__ B = (e < 16) ? (w_gu + (size_t)e * 2 * I_DIM * H_DIM) : s_wgu;

  __shared__ char smem[SMEM_SZ];

  const int tid = threadIdx.x;
  const int lane = tid & 63, wave = tid >> 6;
  const int wm = wave >> 1, wn = wave & 1;
  const int srow = tid >> 1;
  const int scol = (tid & 1) * 16;
  const int l15 = lane & 15;
  const int kq = (lane >> 4) * 8;

  int rloc = mt * 128 + srow;
  int p_eff = poff + (rloc < cnt ? rloc : cnt - 1);
  const float* __restrict__ Arow = x + (size_t)pair_token[p_eff] * H_DIM + scol;
  int brow_g = nt * 64 + (srow < 64 ? srow : 960 + srow);
  const float* __restrict__ Brow = B + (size_t)brow_g * H_DIM + scol;

  f32x4 acc[4][4];
#pragma unroll
  for (int mi = 0; mi < 4; ++mi)
#pragma unroll
    for (int ni = 0; ni < 4; ++ni) { acc[mi][ni][0]=0.f; acc[mi][ni][1]=0.f; acc[mi][ni][2]=0.f; acc[mi][ni][3]=0.f; }

  float4 ar[4], br[4];
#pragma unroll
  for (int i = 0; i < 4; ++i) {
    ar[i] = *(const float4*)(Arow + 4 * i);
    br[i] = *(const float4*)(Brow + 4 * i);
  }
  {
    bf16* As = (bf16*)(smem);
    bf16* Bs = (bf16*)(smem + ABUF);
    *(bf16x8*)(As + srow * LDSS + scol)     = cvt8(ar[0], ar[1]);
    *(bf16x8*)(As + srow * LDSS + scol + 8) = cvt8(ar[2], ar[3]);
    *(bf16x8*)(Bs + srow * LDSS + scol)     = cvt8(br[0], br[1]);
    *(bf16x8*)(Bs + srow * LDSS + scol + 8) = cvt8(br[2], br[3]);
  }
  __syncthreads();
  int cur = 0;
  for (int k0 = BK; ; k0 += BK) {
    const bool more = (k0 < H_DIM);
    if (more) {
#pragma unroll
      for (int i = 0; i < 4; ++i) {
        ar[i] = *(const float4*)(Arow + k0 + 4 * i);
        br[i] = *(const float4*)(Brow + k0 + 4 * i);
      }
    }
    {
      const bf16* As = (const bf16*)(smem + cur * BUFSZ);
      const bf16* Bs = (const bf16*)(smem + cur * BUFSZ + ABUF);
      bf16x8 af[4], bfv[4];
#pragma unroll
      for (int mi = 0; mi < 4; ++mi)
        af[mi] = *(const bf16x8*)(As + (wm * 64 + mi * 16 + l15) * LDSS + kq);
#pragma unroll
      for (int ni = 0; ni < 4; ++ni)
        bfv[ni] = *(const bf16x8*)(Bs + (wn * 64 + ni * 16 + l15) * LDSS + kq);
#pragma unroll
      for (int mi = 0; mi < 4; ++mi)
#pragma unroll
        for (int ni = 0; ni < 4; ++ni)
          acc[mi][ni] = __builtin_amdgcn_mfma_f32_16x16x32_bf16(af[mi], bfv[ni], acc[mi][ni], 0, 0, 0);
    }
    if (more) {
      bf16* As = (bf16*)(smem + (cur ^ 1) * BUFSZ);
      bf16* Bs = (bf16*)(smem + (cur ^ 1) * BUFSZ + ABUF);
      *(bf16x8*)(As + srow * LDSS + scol)     = cvt8(ar[0], ar[1]);
      *(bf16x8*)(As + srow * LDSS + scol + 8) = cvt8(ar[2], ar[3]);
      *(bf16x8*)(Bs + srow * LDSS + scol)     = cvt8(br[0], br[1]);
      *(bf16x8*)(Bs + srow * LDSS + scol + 8) = cvt8(br[2], br[3]);
    }
    __syncthreads();
    cur ^= 1;
    if (!more) break;
  }

  // epilogue: wn==1 waves hold "up" acc; exchange through LDS, wn==0 writes silu(g)*u
  float* u_lds = (float*)smem;  // [128][65] fp32 = 33280 B
  if (wn == 1) {
#pragma unroll
    for (int mi = 0; mi < 4; ++mi)
#pragma unroll
      for (int reg = 0; reg < 4; ++reg) {
        int r = wm * 64 + mi * 16 + (lane >> 4) * 4 + reg;
#pragma unroll
        for (int ni = 0; ni < 4; ++ni)
          u_lds[r * 65 + ni * 16 + l15] = acc[mi][ni][reg];
      }
  }
  __syncthreads();
  if (wn == 0) {
#pragma unroll
    for (int mi = 0; mi < 4; ++mi)
#pragma unroll
      for (int reg = 0; reg < 4; ++reg) {
        int r = wm * 64 + mi * 16 + (lane >> 4) * 4 + reg;
        int rl = mt * 128 + r;
        if (rl < cnt) {
          bf16* orow = a_buf + (size_t)(poff + rl) * I_DIM + nt * 64 + l15;
#pragma unroll
          for (int ni = 0; ni < 4; ++ni) {
            float g = acc[mi][ni][reg];
            float u = u_lds[r * 65 + ni * 16 + l15];
            float s = g / (1.f + __expf(-g));
            orow[ni * 16] = (bf16)(s * u);
          }
        }
      }
  }
}

// ---------------- down GEMM -> per-pair partials (no atomics) ----------------
__global__ __launch_bounds__(256) void down_kernel(
    const bf16* __restrict__ a_buf, const float* __restrict__ w_dn,
    const float* __restrict__ s_wdn,
    const int* __restrict__ off, const float* __restrict__ pair_scale,
    bf16* __restrict__ dpart)
{
  const int nt = blockIdx.x;   // 0..15 over H (128 cols each)
  const int mt = blockIdx.y;   // 0..7
  const int e  = blockIdx.z;   // 0..16
  const int poff = (e < 16) ? off[e]     : NPAIR_R;
  const int pend = (e < 16) ? off[e + 1] : NPAIR;
  const int cnt  = pend - poff;
  if (mt * 128 >= cnt) return;
  const float* __restrict__ B = (e < 16) ? (w_dn + (size_t)e * H_DIM * I_DIM) : s_wdn;

  __shared__ char smem[SMEM_SZ];

  const int tid = threadIdx.x;
  const int lane = tid & 63, wave = tid >> 6;
  const int wm = wave >> 1, wn = wave & 1;
  const int srow = tid >> 1;
  const int scol = (tid & 1) * 16;
  const int l15 = lane & 15;
  const int kq = (lane >> 4) * 8;

  int rloc = mt * 128 + srow;
  int r_eff = poff + (rloc < cnt ? rloc : cnt - 1);
  const bf16* __restrict__ Arow = a_buf + (size_t)r_eff * I_DIM + scol;
  const float* __restrict__ Brow = B + (size_t)(nt * 128 + srow) * I_DIM + scol;

  f32x4 acc[4][4];
#pragma unroll
  for (int mi = 0; mi < 4; ++mi)
#pragma unroll
    for (int ni = 0; ni < 4; ++ni) { acc[mi][ni][0]=0.f; acc[mi][ni][1]=0.f; acc[mi][ni][2]=0.f; acc[mi][ni][3]=0.f; }

  bf16x8 a0, a1; float4 br[4];
  a0 = *(const bf16x8*)(Arow);
  a1 = *(const bf16x8*)(Arow + 8);
#pragma unroll
  for (int i = 0; i < 4; ++i) br[i] = *(const float4*)(Brow + 4 * i);
  {
    bf16* As = (bf16*)(smem);
    bf16* Bs = (bf16*)(smem + ABUF);
    *(bf16x8*)(As + srow * LDSS + scol)     = a0;
    *(bf16x8*)(As + srow * LDSS + scol + 8) = a1;
    *(bf16x8*)(Bs + srow * LDSS + scol)     = cvt8(br[0], br[1]);
    *(bf16x8*)(Bs + srow * LDSS + scol + 8) = cvt8(br[2], br[3]);
  }
  __syncthreads();
  int cur = 0;
  for (int k0 = BK; ; k0 += BK) {
    const bool more = (k0 < I_DIM);
    if (more) {
      a0 = *(const bf16x8*)(Arow + k0);
      a1 = *(const bf16x8*)(Arow + k0 + 8);
#pragma unroll
      for (int i = 0; i < 4; ++i) br[i] = *(const float4*)(Brow + k0 + 4 * i);
    }
    {
      const bf16* As = (const bf16*)(smem + cur * BUFSZ);
      const bf16* Bs = (const bf16*)(smem + cur * BUFSZ + ABUF);
      bf16x8 af[4], bfv[4];
#pragma unroll
      for (int mi = 0; mi < 4; ++mi)
        af[mi] = *(const bf16x8*)(As + (wm * 64 + mi * 16 + l15) * LDSS + kq);
#pragma unroll
      for (int ni = 0; ni < 4; ++ni)
        bfv[ni] = *(const bf16x8*)(Bs + (wn * 64 + ni * 16 + l15) * LDSS + kq);
#pragma unroll
      for (int mi = 0; mi < 4; ++mi)
#pragma unroll
        for (int ni = 0; ni < 4; ++ni)
          acc[mi][ni] = __builtin_amdgcn_mfma_f32_16x16x32_bf16(af[mi], bfv[ni], acc[mi][ni], 0, 0, 0);
    }
    if (more) {
      bf16* As = (bf16*)(smem + (cur ^ 1) * BUFSZ);
      bf16* Bs = (bf16*)(smem + (cur ^ 1) * BUFSZ + ABUF);
      *(bf16x8*)(As + srow * LDSS + scol)     = a0;
      *(bf16x8*)(As + srow * LDSS + scol + 8) = a1;
      *(bf16x8*)(Bs + srow * LDSS + scol)     = cvt8(br[0], br[1]);
      *(bf16x8*)(Bs + srow * LDSS + scol + 8) = cvt8(br[2], br[3]);
    }
    __syncthreads();
    cur ^= 1;
    if (!more) break;
  }

  const int colb = nt * 128 + wn * 64;
#pragma unroll
  for (int mi = 0; mi < 4; ++mi) {
#pragma unroll
    for (int reg = 0; reg < 4; ++reg) {
      int r = wm * 64 + mi * 16 + (lane >> 4) * 4 + reg;
      int rl = mt * 128 + r;
      if (rl < cnt) {
        int p = poff + rl;
        float sc = pair_scale[p];
        bf16* orow = dpart + (size_t)p * H_DIM + colb + l15;
#pragma unroll
        for (int ni = 0; ni < 4; ++ni)
          orow[ni * 16] = (bf16)(acc[mi][ni][reg] * sc);
      }
    }
  }
}

// ---------------- combine: out[t,h] = sum of 5 scaled partial rows ----------------
__global__ __launch_bounds__(256) void combine_kernel(
    const bf16* __restrict__ dpart, const int* __restrict__ inv_pair,
    float* __restrict__ out)
{
  int i = (blockIdx.x * 256 + threadIdx.x) * 4;
  int t = i >> 11;
  int h = i & 2047;
  const int* iv = inv_pair + t * 5;
  float4 s = {0.f, 0.f, 0.f, 0.f};
#pragma unroll
  for (int j = 0; j < 5; ++j) {
    bf16x4 d = *(const bf16x4*)(dpart + (size_t)iv[j] * H_DIM + h);
    s.x += (float)d[0]; s.y += (float)d[1]; s.z += (float)d[2]; s.w += (float)d[3];
  }
  *(float4*)(out + i) = s;
}

// ---------------- launch ----------------
extern "C" void kernel_launch(void* const* d_in, const int* in_sizes, int n_in,
                              void* d_out, int out_size, void* d_ws, size_t ws_size,
                              hipStream_t stream)
{
  const float* x     = (const float*)d_in[0];
  const float* gatew = (const float*)d_in[1];
  const float* ebias = (const float*)d_in[2];
  const float* w_gu  = (const float*)d_in[3];
  const float* w_dn  = (const float*)d_in[4];
  const float* s_wgu = (const float*)d_in[5];
  const float* s_wdn = (const float*)d_in[6];
  float* out = (float*)d_out;

  char* ws = (char*)d_ws;
  int*   off        = (int*)(ws + 0);          // 17 ints
  int*   counts     = (int*)(ws + 128);        // 16 ints
  int*   cursor     = (int*)(ws + 192);        // 16 ints
  int*   topk_ids   = (int*)(ws + 256);        // 4096 ints
  float* topk_w     = (float*)(ws + 16640);    // 4096 floats
  int*   pair_token = (int*)(ws + 33024);      // 5120 ints
  float* pair_scale = (float*)(ws + 53504);    // 5120 floats
  int*   inv_pair   = (int*)(ws + 73984);      // 5120 ints
  bf16*  a_buf      = (bf16*)(ws + 94464);     // 5120*1024 bf16 = 10,485,760 B
  bf16*  dpart      = (bf16*)(ws + 10580224);  // 5120*2048 bf16 = 20,971,520 B

  hipMemsetAsync(ws + 128, 0, 128, stream);    // counts + cursor

  router_kernel<<<T_TOK, 256, 0, stream>>>(x, gatew, ebias, topk_ids, topk_w, counts);
  offsets_kernel<<<1, 64, 0, stream>>>(counts, off);
  scatter_kernel<<<NPAIR / 256, 256, 0, stream>>>(topk_ids, topk_w, off, cursor,
                                                  pair_token, pair_scale, inv_pair);
  dim3 g1(16, 8, 17);
  gateup_silu_kernel<<<g1, 256, 0, stream>>>(x, w_gu, s_wgu, off, pair_token, a_buf);
  dim3 g2(16, 8, 17);
  down_kernel<<<g2, 256, 0, stream>>>(a_buf, w_dn, s_wdn, off, pair_scale, dpart);
  combine_kernel<<<(T_TOK * H_DIM) / (256 * 4), 256, 0, stream>>>(dpart, inv_pair, out);
}

// Round 3
// 679.194 us; speedup vs baseline: 1.0132x; 1.0132x over previous
//
#include <hip/hip_runtime.h>
#include <math.h>

typedef __bf16 bf16;
typedef bf16 bf16x4 __attribute__((ext_vector_type(4)));
typedef bf16 bf16x8 __attribute__((ext_vector_type(8)));
typedef float f32x4 __attribute__((ext_vector_type(4)));

#define T_TOK   1024
#define H_DIM   2048
#define I_DIM   1024
#define NPAIR_R 4096
#define NPAIR   5120

typedef __attribute__((address_space(3))) void lds_void;
typedef const __attribute__((address_space(1))) void glob_void;

__device__ __forceinline__ void gl16(const void* g, void* l) {
  __builtin_amdgcn_global_load_lds((glob_void*)g, (lds_void*)l, 16, 0, 0);
}

__device__ __forceinline__ bf16x8 cvt8(const float4 a, const float4 b) {
  bf16x8 r;
  r[0] = (bf16)a.x; r[1] = (bf16)a.y; r[2] = (bf16)a.z; r[3] = (bf16)a.w;
  r[4] = (bf16)b.x; r[5] = (bf16)b.y; r[6] = (bf16)b.z; r[7] = (bf16)b.w;
  return r;
}

// ---------------- router ----------------
__global__ __launch_bounds__(256) void router_kernel(
    const float* __restrict__ x, const float* __restrict__ gate_w,
    const float* __restrict__ e_bias,
    int* __restrict__ topk_ids, float* __restrict__ topk_w,
    int* __restrict__ counts)
{
  int t = blockIdx.x;
  int tid = threadIdx.x;
  float acc[16];
#pragma unroll
  for (int e = 0; e < 16; ++e) acc[e] = 0.f;
  const float* xr = x + (size_t)t * H_DIM;
  for (int h = tid; h < H_DIM; h += 256) {
    float xv = xr[h];
#pragma unroll
    for (int e = 0; e < 16; ++e) acc[e] += xv * gate_w[e * H_DIM + h];
  }
#pragma unroll
  for (int e = 0; e < 16; ++e) {
#pragma unroll
    for (int off = 32; off >= 1; off >>= 1)
      acc[e] += __shfl_down(acc[e], off, 64);
  }
  __shared__ float red[4][16];
  int lane = tid & 63, wave = tid >> 6;
  if (lane == 0) {
#pragma unroll
    for (int e = 0; e < 16; ++e) red[wave][e] = acc[e];
  }
  __syncthreads();
  if (tid == 0) {
    float scores[16], sb[16];
    for (int e = 0; e < 16; ++e) {
      float l = red[0][e] + red[1][e] + red[2][e] + red[3][e];
      float s = 1.f / (1.f + expf(-l));
      scores[e] = s;
      sb[e] = s + e_bias[e];
    }
    float gs[4];
    for (int g = 0; g < 4; ++g) {
      float b1 = -1e30f, b2 = -1e30f;
      for (int j = 0; j < 4; ++j) {
        float v = sb[g * 4 + j];
        if (v > b1) { b2 = b1; b1 = v; }
        else if (v > b2) b2 = v;
      }
      gs[g] = b1 + b2;
    }
    int g1 = 0; float bv = gs[0];
    for (int g = 1; g < 4; ++g) if (gs[g] > bv) { bv = gs[g]; g1 = g; }
    int g2 = -1; float bv2 = -1e30f;
    for (int g = 0; g < 4; ++g) if (g != g1 && gs[g] > bv2) { bv2 = gs[g]; g2 = g; }
    float tmp[16];
    for (int e = 0; e < 16; ++e) {
      int grp = e >> 2;
      tmp[e] = (grp == g1 || grp == g2) ? sb[e] : 0.0f;
    }
    bool used[16] = {false};
    int ids[4]; float wv[4]; float wsum = 0.f;
    for (int k = 0; k < 4; ++k) {
      int bi = 0; float bvv = -1e30f;
      for (int i = 0; i < 16; ++i)
        if (!used[i] && tmp[i] > bvv) { bvv = tmp[i]; bi = i; }
      used[bi] = true;
      ids[k] = bi; wv[k] = scores[bi]; wsum += scores[bi];
    }
    float inv = 1.f / wsum;
    for (int k = 0; k < 4; ++k) {
      topk_ids[t * 4 + k] = ids[k];
      topk_w[t * 4 + k] = wv[k] * inv;
      atomicAdd(&counts[ids[k]], 1);
    }
  }
}

// ---------------- offsets ----------------
__global__ void offsets_kernel(const int* __restrict__ counts, int* __restrict__ off)
{
  if (threadIdx.x == 0 && blockIdx.x == 0) {
    int s = 0;
    for (int e = 0; e < 16; ++e) { off[e] = s; s += counts[e]; }
    off[16] = s;
  }
}

// ---------------- scatter + inverse map ----------------
__global__ __launch_bounds__(256) void scatter_kernel(
    const int* __restrict__ topk_ids, const float* __restrict__ topk_w,
    const int* __restrict__ off, int* __restrict__ cursor,
    int* __restrict__ pair_token, float* __restrict__ pair_scale,
    int* __restrict__ inv_pair)
{
  int i = blockIdx.x * 256 + threadIdx.x;
  if (i < NPAIR_R) {
    int e = topk_ids[i];
    float w = topk_w[i];
    int pos = atomicAdd(&cursor[e], 1);
    int idx = off[e] + pos;
    int t = i >> 2;
    pair_token[idx] = t;
    pair_scale[idx] = 2.5f * w;
    inv_pair[t * 5 + (i & 3)] = idx;
  } else if (i < NPAIR) {
    int t = i - NPAIR_R;
    pair_token[i] = t;
    pair_scale[i] = 1.0f;
    inv_pair[t * 5 + 4] = i;
  }
}

// ---------------- fused gate_up GEMM + in-register SiLU*mul ----------------
// Tile: M=64 pair-rows, 64 a-cols (= 128 weight rows: 64 gate + 64 up), BK=32.
// LDS: A fp32 [64][32] unpadded, XOR-swizzled; B fp32 [128][32] unpadded, swizzled.
// Staged via global_load_lds(16B); bf16 convert on fragment read.
__global__ __launch_bounds__(256) void gateup_silu_kernel(
    const float* __restrict__ x, const float* __restrict__ w_gu,
    const float* __restrict__ s_wgu,
    const int* __restrict__ off, const int* __restrict__ pair_token,
    bf16* __restrict__ a_buf)
{
  const int nt = blockIdx.x;              // 16 tiles of 64 a-cols
  const int mt = blockIdx.y;              // 16 tiles of 64 rows
  const int ez = blockIdx.z;
  const int e  = (ez == 0) ? 16 : ez - 1; // shared expert (largest M) first
  const int poff = (e < 16) ? off[e]     : NPAIR_R;
  const int pend = (e < 16) ? off[e + 1] : NPAIR;
  const int cnt  = pend - poff;
  if (mt * 64 >= cnt) return;
  const float* __restrict__ B = (e < 16) ? (w_gu + (size_t)e * (2 * I_DIM) * H_DIM) : s_wgu;

  __shared__ __attribute__((aligned(16))) char smem[24576]; // A 8KB @0, B 16KB @8192

  const int tid = threadIdx.x;
  const int lane = tid & 63, wave = tid >> 6;
  const int wm = wave >> 1, wn = wave & 1;
  const int l15 = lane & 15, q = lane >> 4;

  // staging sources: lane covers LDS bytes (wavebase + lane*16); decode row/chunk,
  // un-swizzle to find which global 16B belongs there.
  const float* a_src[2];
#pragma unroll
  for (int i = 0; i < 2; ++i) {
    int flat = wave * 2048 + i * 1024 + lane * 16;
    int r = flat >> 7;                          // 128B rows (32 fp32)
    int c = ((flat >> 4) & 7) ^ (r & 7);
    int rg = mt * 64 + r; if (rg >= cnt) rg = cnt - 1;
    a_src[i] = x + (size_t)pair_token[poff + rg] * H_DIM + c * 4;
  }
  const float* b_src[4];
#pragma unroll
  for (int j = 0; j < 4; ++j) {
    int flat = wave * 4096 + j * 1024 + lane * 16;
    int r = flat >> 7;
    int c = ((flat >> 4) & 7) ^ (r & 7);
    int brow = nt * 64 + ((r < 64) ? r : (960 + r));  // gate rows then up rows (+1024-64)
    b_src[j] = B + (size_t)brow * H_DIM + c * 4;
  }
  char* aw = smem + wave * 2048;
  char* bw = smem + 8192 + wave * 4096;

  f32x4 accg[2][2], accu[2][2];
#pragma unroll
  for (int mi = 0; mi < 2; ++mi)
#pragma unroll
    for (int ni = 0; ni < 2; ++ni) {
      accg[mi][ni][0]=0.f; accg[mi][ni][1]=0.f; accg[mi][ni][2]=0.f; accg[mi][ni][3]=0.f;
      accu[mi][ni][0]=0.f; accu[mi][ni][1]=0.f; accu[mi][ni][2]=0.f; accu[mi][ni][3]=0.f;
    }

  for (int k0 = 0; k0 < H_DIM; k0 += 32) {
    gl16(a_src[0] + k0, aw);
    gl16(a_src[1] + k0, aw + 1024);
#pragma unroll
    for (int j = 0; j < 4; ++j) gl16(b_src[j] + k0, bw + j * 1024);
    __syncthreads();

    bf16x8 af[2], bg[2], bu[2];
#pragma unroll
    for (int mi = 0; mi < 2; ++mi) {
      int r = wm * 32 + mi * 16 + l15;
      int c0 = (2 * q) ^ (r & 7), c1 = (2 * q + 1) ^ (r & 7);
      float4 v0 = *(const float4*)(smem + r * 128 + c0 * 16);
      float4 v1 = *(const float4*)(smem + r * 128 + c1 * 16);
      af[mi] = cvt8(v0, v1);
    }
#pragma unroll
    for (int ni = 0; ni < 2; ++ni) {
      int rg2 = wn * 32 + ni * 16 + l15;
      {
        int c0 = (2 * q) ^ (rg2 & 7), c1 = (2 * q + 1) ^ (rg2 & 7);
        float4 v0 = *(const float4*)(smem + 8192 + rg2 * 128 + c0 * 16);
        float4 v1 = *(const float4*)(smem + 8192 + rg2 * 128 + c1 * 16);
        bg[ni] = cvt8(v0, v1);
      }
      int ru = 64 + rg2;
      {
        int c0 = (2 * q) ^ (ru & 7), c1 = (2 * q + 1) ^ (ru & 7);
        float4 v0 = *(const float4*)(smem + 8192 + ru * 128 + c0 * 16);
        float4 v1 = *(const float4*)(smem + 8192 + ru * 128 + c1 * 16);
        bu[ni] = cvt8(v0, v1);
      }
    }
#pragma unroll
    for (int mi = 0; mi < 2; ++mi)
#pragma unroll
      for (int ni = 0; ni < 2; ++ni) {
        accg[mi][ni] = __builtin_amdgcn_mfma_f32_16x16x32_bf16(af[mi], bg[ni], accg[mi][ni], 0, 0, 0);
        accu[mi][ni] = __builtin_amdgcn_mfma_f32_16x16x32_bf16(af[mi], bu[ni], accu[mi][ni], 0, 0, 0);
      }
    __syncthreads();
  }

  // epilogue: silu(g)*u in-register (same wave owns matching gate/up cols)
#pragma unroll
  for (int mi = 0; mi < 2; ++mi)
#pragma unroll
    for (int reg = 0; reg < 4; ++reg) {
      int rr = wm * 32 + mi * 16 + q * 4 + reg;
      int rg = mt * 64 + rr;
      if (rg < cnt) {
        bf16* orow = a_buf + (size_t)(poff + rg) * I_DIM + nt * 64 + wn * 32 + l15;
#pragma unroll
        for (int ni = 0; ni < 2; ++ni) {
          float g = accg[mi][ni][reg];
          float u = accu[mi][ni][reg];
          orow[ni * 16] = (bf16)(g / (1.f + __expf(-g)) * u);
        }
      }
    }
}

// ---------------- down GEMM -> per-pair partials ----------------
// Tile: M=64 rows, N=128 H-cols, BK=32. A bf16 DMA'd, B fp32 DMA'd+read-cvt.
__global__ __launch_bounds__(256) void down_kernel(
    const bf16* __restrict__ a_buf, const float* __restrict__ w_dn,
    const float* __restrict__ s_wdn,
    const int* __restrict__ off, const float* __restrict__ pair_scale,
    bf16* __restrict__ dpart)
{
  const int nt = blockIdx.x;              // 16 tiles of 128 H-cols
  const int mt = blockIdx.y;              // 16 tiles of 64 rows
  const int ez = blockIdx.z;
  const int e  = (ez == 0) ? 16 : ez - 1;
  const int poff = (e < 16) ? off[e]     : NPAIR_R;
  const int pend = (e < 16) ? off[e + 1] : NPAIR;
  const int cnt  = pend - poff;
  if (mt * 64 >= cnt) return;
  const float* __restrict__ B = (e < 16) ? (w_dn + (size_t)e * H_DIM * I_DIM) : s_wdn;

  __shared__ __attribute__((aligned(16))) char smem[20480]; // A bf16 4KB @0, B fp32 16KB @4096

  const int tid = threadIdx.x;
  const int lane = tid & 63, wave = tid >> 6;
  const int wm = wave >> 1, wn = wave & 1;
  const int l15 = lane & 15, q = lane >> 4;

  // A staging: bf16 tile [64][32] (64B rows, 4 chunks), swizzle c ^ ((r>>1)&3)
  const bf16* a_src;
  {
    int flat = wave * 1024 + lane * 16;
    int r = flat >> 6;
    int c = ((flat >> 4) & 3) ^ ((r >> 1) & 3);
    int rg = mt * 64 + r; if (rg >= cnt) rg = cnt - 1;
    a_src = a_buf + (size_t)(poff + rg) * I_DIM + c * 8;
  }
  const float* b_src[4];
#pragma unroll
  for (int j = 0; j < 4; ++j) {
    int flat = wave * 4096 + j * 1024 + lane * 16;
    int r = flat >> 7;
    int c = ((flat >> 4) & 7) ^ (r & 7);
    b_src[j] = B + (size_t)(nt * 128 + r) * I_DIM + c * 4;
  }
  char* aw = smem + wave * 1024;
  char* bw = smem + 4096 + wave * 4096;

  f32x4 acc[2][4];
#pragma unroll
  for (int mi = 0; mi < 2; ++mi)
#pragma unroll
    for (int ni = 0; ni < 4; ++ni) { acc[mi][ni][0]=0.f; acc[mi][ni][1]=0.f; acc[mi][ni][2]=0.f; acc[mi][ni][3]=0.f; }

  for (int k0 = 0; k0 < I_DIM; k0 += 32) {
    gl16(a_src + k0, aw);
#pragma unroll
    for (int j = 0; j < 4; ++j) gl16(b_src[j] + k0, bw + j * 1024);
    __syncthreads();

    bf16x8 af[2], bfv[4];
#pragma unroll
    for (int mi = 0; mi < 2; ++mi) {
      int r = wm * 32 + mi * 16 + l15;
      int c = q ^ ((r >> 1) & 3);
      af[mi] = *(const bf16x8*)(smem + r * 64 + c * 16);
    }
#pragma unroll
    for (int ni = 0; ni < 4; ++ni) {
      int r = wn * 64 + ni * 16 + l15;
      int c0 = (2 * q) ^ (r & 7), c1 = (2 * q + 1) ^ (r & 7);
      float4 v0 = *(const float4*)(smem + 4096 + r * 128 + c0 * 16);
      float4 v1 = *(const float4*)(smem + 4096 + r * 128 + c1 * 16);
      bfv[ni] = cvt8(v0, v1);
    }
#pragma unroll
    for (int mi = 0; mi < 2; ++mi)
#pragma unroll
      for (int ni = 0; ni < 4; ++ni)
        acc[mi][ni] = __builtin_amdgcn_mfma_f32_16x16x32_bf16(af[mi], bfv[ni], acc[mi][ni], 0, 0, 0);
    __syncthreads();
  }

#pragma unroll
  for (int mi = 0; mi < 2; ++mi)
#pragma unroll
    for (int reg = 0; reg < 4; ++reg) {
      int rr = wm * 32 + mi * 16 + q * 4 + reg;
      int rg = mt * 64 + rr;
      if (rg < cnt) {
        int p = poff + rg;
        float sc = pair_scale[p];
        bf16* orow = dpart + (size_t)p * H_DIM + nt * 128 + wn * 64 + l15;
#pragma unroll
        for (int ni = 0; ni < 4; ++ni)
          orow[ni * 16] = (bf16)(acc[mi][ni][reg] * sc);
      }
    }
}

// ---------------- combine ----------------
__global__ __launch_bounds__(256) void combine_kernel(
    const bf16* __restrict__ dpart, const int* __restrict__ inv_pair,
    float* __restrict__ out)
{
  int i = (blockIdx.x * 256 + threadIdx.x) * 4;
  int t = i >> 11;
  int h = i & 2047;
  const int* iv = inv_pair + t * 5;
  float4 s = {0.f, 0.f, 0.f, 0.f};
#pragma unroll
  for (int j = 0; j < 5; ++j) {
    bf16x4 d = *(const bf16x4*)(dpart + (size_t)iv[j] * H_DIM + h);
    s.x += (float)d[0]; s.y += (float)d[1]; s.z += (float)d[2]; s.w += (float)d[3];
  }
  *(float4*)(out + i) = s;
}

// ---------------- launch ----------------
extern "C" void kernel_launch(void* const* d_in, const int* in_sizes, int n_in,
                              void* d_out, int out_size, void* d_ws, size_t ws_size,
                              hipStream_t stream)
{
  const float* x     = (const float*)d_in[0];
  const float* gatew = (const float*)d_in[1];
  const float* ebias = (const float*)d_in[2];
  const float* w_gu  = (const float*)d_in[3];
  const float* w_dn  = (const float*)d_in[4];
  const float* s_wgu = (const float*)d_in[5];
  const float* s_wdn = (const float*)d_in[6];
  float* out = (float*)d_out;

  char* ws = (char*)d_ws;
  int*   off        = (int*)(ws + 0);
  int*   topk_ids   = (int*)(ws + 256);
  float* topk_w     = (float*)(ws + 16640);
  int*   pair_token = (int*)(ws + 33024);
  float* pair_scale = (float*)(ws + 53504);
  int*   inv_pair   = (int*)(ws + 73984);
  bf16*  a_buf      = (bf16*)(ws + 94464);     // 5120*1024 bf16
  bf16*  dpart      = (bf16*)(ws + 10580224);  // 5120*2048 bf16
  int*   counts     = (int*)(ws + 128);
  int*   cursor     = (int*)(ws + 192);

  hipMemsetAsync(ws + 128, 0, 128, stream);

  router_kernel<<<T_TOK, 256, 0, stream>>>(x, gatew, ebias, topk_ids, topk_w, counts);
  offsets_kernel<<<1, 64, 0, stream>>>(counts, off);
  scatter_kernel<<<NPAIR / 256, 256, 0, stream>>>(topk_ids, topk_w, off, cursor,
                                                  pair_token, pair_scale, inv_pair);
  dim3 g1(16, 16, 17);
  gateup_silu_kernel<<<g1, 256, 0, stream>>>(x, w_gu, s_wgu, off, pair_token, a_buf);
  dim3 g2(16, 16, 17);
  down_kernel<<<g2, 256, 0, stream>>>(a_buf, w_dn, s_wdn, off, pair_scale, dpart);
  combine_kernel<<<(T_TOK * H_DIM) / (256 * 4), 256, 0, stream>>>(dpart, inv_pair, out);
}